// Round 1
// baseline (12966.440 us; speedup 1.0000x reference)
//
#include <hip/hip_runtime.h>
#include <hip/hip_bf16.h>

// ---------------------------------------------------------------------------
// LSTM (B=32, T=2048, I=256, H=512), batch_first, fp32 in/out.
// Strategy: persistent cooperative kernel, weights register-resident as MFMA
// B-fragments (fp16), h broadcast via global fragment-major fp16 buffer,
// custom agent-scope barrier per timestep.
// ---------------------------------------------------------------------------

typedef _Float16 f16x8 __attribute__((ext_vector_type(8)));
typedef float    f32x16 __attribute__((ext_vector_type(16)));

#define NBLK   32
#define TSTEPS 2048

// ws layout (bytes)
#define WS_WH    0            // 4*512*512*2   = 2,097,152
#define WS_WX    2097152      // 4*512*256*2   = 1,048,576
#define WS_XG    3145728      // 2048*16*64*8*2= 33,554,432
#define WS_HG    36700160     // 2*32*64*8*2   = 65,536
#define WS_BIAS  36765696     // 4*512*4       = 8,192
#define WS_CNT   36773888

#define OUT_MAIN 33554432     // 512*65536
#define OFF_HN   (OUT_MAIN)
#define OFF_CN   (OUT_MAIN + 16384)
#define OFF_IG   (OUT_MAIN + 32768)
#define OFF_FG   (OUT_MAIN + 49152)
#define OFF_OG   (OUT_MAIN + 65536)

struct Ptrs { const float* p[16]; };   // p[0..7]=Wii,bii,..Wio,bio  p[8..15]=Whi,bhi,..Who,bho

__device__ __forceinline__ float sigf(float v) {
    return 1.0f / (1.0f + __expf(-v));
}
__device__ __forceinline__ float tanhf_(float v) {
    float a = fabsf(v);
    float e = __expf(-2.0f * a);
    float r = (1.0f - e) / (1.0f + e);
    return v < 0.0f ? -r : r;
}

// ---------------------------------------------------------------------------
// Setup: convert weights to fp16, combine biases, init h fragment buffer, cnt
// ---------------------------------------------------------------------------
__global__ void setup_kernel(Ptrs P, const float* __restrict__ hx,
                             _Float16* __restrict__ WH16, _Float16* __restrict__ WX16,
                             float* __restrict__ BIAS, _Float16* __restrict__ HG,
                             unsigned* __restrict__ CNT)
{
    int idx = blockIdx.x * 256 + threadIdx.x;
    if (idx < 1048576) {                       // WH16[g][j][k] <- Whg (row-major copy)
        int g = idx >> 18; int r = idx & 262143;
        WH16[idx] = (_Float16)P.p[8 + 2*g][r];
    } else if (idx < 1572864) {                // WX16[g][j][i]
        int j = idx - 1048576; int g = j >> 17; int r = j & 131071;
        WX16[j] = (_Float16)P.p[2*g][r];
    } else if (idx < 1574912) {                // combined bias
        int j = idx - 1572864; int g = j >> 9; int c = j & 511;
        BIAS[j] = P.p[2*g + 1][c] + P.p[8 + 2*g + 1][c];
    } else if (idx < 1576960) {                // h0 fragment-major chunks
        int ch = idx - 1574912;                // 0..2047 : [kf 0..31][lane 0..63]
        int kf = ch >> 6; int lane = ch & 63;
        int b = lane & 31; int k0 = (kf*2 + (lane >> 5)) * 8;
        f16x8 o;
        #pragma unroll
        for (int e = 0; e < 8; ++e) o[e] = (_Float16)hx[b*512 + k0 + e];
        *(f16x8*)(HG + (size_t)ch * 8) = o;
    } else if (idx == 1576960) {
        *CNT = 0u;
    }
}

// ---------------------------------------------------------------------------
// x -> fp16 fragment-major per step: XG[t][kf 0..15][lane 0..63][8]
// ---------------------------------------------------------------------------
__global__ void xconv_kernel(const float* __restrict__ x, _Float16* __restrict__ XG)
{
    int ch = blockIdx.x * 256 + threadIdx.x;   // 0 .. 2,097,151
    int t = ch >> 10; int rest = ch & 1023;
    int kf = rest >> 6; int lane = rest & 63;
    int b = lane & 31; int i0 = (kf*2 + (lane >> 5)) * 8;
    const float* src = x + ((size_t)b * 2048 + t) * 256 + i0;
    float4 u = *(const float4*)src;
    float4 v = *(const float4*)(src + 4);
    f16x8 o;
    o[0]=(_Float16)u.x; o[1]=(_Float16)u.y; o[2]=(_Float16)u.z; o[3]=(_Float16)u.w;
    o[4]=(_Float16)v.x; o[5]=(_Float16)v.y; o[6]=(_Float16)v.z; o[7]=(_Float16)v.w;
    *(f16x8*)(XG + (size_t)ch * 8) = o;
}

// ---------------------------------------------------------------------------
// Persistent recurrent kernel: 32 blocks x 256 threads
// block bk owns h-cols [bk*16, bk*16+16) for all 4 gates (64 gate-cols)
// wave w: kh = w&1 (K-half of 768=512h+256x), cs = w>>1 (colset of 32)
// ---------------------------------------------------------------------------
__global__ __launch_bounds__(256, 1) void lstm_rec(
    const float* __restrict__ cx, float* __restrict__ out,
    const _Float16* __restrict__ WH16, const _Float16* __restrict__ WX16,
    const _Float16* __restrict__ XG, _Float16* __restrict__ HG,
    const float* __restrict__ BIAS, unsigned* __restrict__ CNT)
{
    __shared__ float part[2][32][66];
    __shared__ float bias_lds[4][16];

    const int tid = threadIdx.x;
    const int bk  = blockIdx.x;
    const int jbase = bk * 16;
    const int w  = tid >> 6;
    const int l  = tid & 63;
    const int kh = w & 1;
    const int cs = w >> 1;
    const int n  = l & 31;
    const int kg = l >> 5;

    if (tid < 64) bias_lds[tid >> 4][tid & 15] = BIAS[(tid >> 4)*512 + jbase + (tid & 15)];

    // ---- register-resident weights: 24 B-fragments per wave ----
    const int c_loc = cs*32 + n;          // local gate-col 0..63
    const int g  = c_loc >> 4;            // gate 0..3
    const int jr = jbase + (c_loc & 15);  // weight row (output col j)

    f16x8 bf[24];
    #pragma unroll
    for (int m = 0; m < 16; ++m) {        // h part: k = (kh*16+m)*16 + kg*8
        int k = (kh*16 + m)*16 + kg*8;
        bf[m] = *(const f16x8*)(WH16 + ((size_t)g*512 + jr)*512 + k);
    }
    #pragma unroll
    for (int m = 0; m < 8; ++m) {         // x part
        int i = (kh*8 + m)*16 + kg*8;
        bf[16 + m] = *(const f16x8*)(WX16 + ((size_t)g*512 + jr)*256 + i);
    }

    // ---- elementwise ownership: (b=eb, j=jbase+ej) and (b=eb, j=jbase+ej+8) ----
    const int eb = tid & 31;
    const int ej = tid >> 5;              // 0..7
    float c0 = cx[eb*512 + jbase + ej];
    float c1 = cx[eb*512 + jbase + ej + 8];

    __syncthreads();

    for (int t = 0; t < TSTEPS; ++t) {
        const _Float16* hcur = HG + (size_t)(t & 1) * 16384;

        // A fragments: coalesced 16B/lane from fragment-major buffers
        f16x8 ah[16], ax[8];
        #pragma unroll
        for (int m = 0; m < 8; ++m)
            ax[m] = *(const f16x8*)(XG + (size_t)t*8192 + (size_t)(kh*8 + m)*512 + l*8);
        #pragma unroll
        for (int m = 0; m < 16; ++m)
            ah[m] = *(const f16x8*)(hcur + (size_t)(kh*16 + m)*512 + l*8);

        f32x16 accA, accB;
        #pragma unroll
        for (int i = 0; i < 16; ++i) { accA[i] = 0.0f; accB[i] = 0.0f; }

        // x-part first (data tends to be ready first), two interleaved chains
        #pragma unroll
        for (int m = 0; m < 8; m += 2) {
            accA = __builtin_amdgcn_mfma_f32_32x32x16_f16(ax[m],   bf[16+m],   accA, 0, 0, 0);
            accB = __builtin_amdgcn_mfma_f32_32x32x16_f16(ax[m+1], bf[16+m+1], accB, 0, 0, 0);
        }
        #pragma unroll
        for (int m = 0; m < 16; m += 2) {
            accA = __builtin_amdgcn_mfma_f32_32x32x16_f16(ah[m],   bf[m],   accA, 0, 0, 0);
            accB = __builtin_amdgcn_mfma_f32_32x32x16_f16(ah[m+1], bf[m+1], accB, 0, 0, 0);
        }

        // partial gate pre-activations -> LDS (D layout: col=l&31, row=(r&3)+8*(r>>2)+4*kg)
        #pragma unroll
        for (int r = 0; r < 16; ++r) {
            int b = (r & 3) + 8*(r >> 2) + 4*kg;
            part[kh][b][c_loc] = accA[r] + accB[r];
        }
        __syncthreads();

        // ---- elementwise: reduce K-halves, activations, state update ----
        _Float16* hnxt = HG + (size_t)((t + 1) & 1) * 16384;
        float hy0, hy1;
        {
            float v0 = part[0][eb][ 0 + ej] + part[1][eb][ 0 + ej] + bias_lds[0][ej];
            float v1 = part[0][eb][16 + ej] + part[1][eb][16 + ej] + bias_lds[1][ej];
            float v2 = part[0][eb][32 + ej] + part[1][eb][32 + ej] + bias_lds[2][ej];
            float v3 = part[0][eb][48 + ej] + part[1][eb][48 + ej] + bias_lds[3][ej];
            float ig = sigf(v0), fg = sigf(v1), cg = tanhf_(v2), og = sigf(v3);
            c0 = fg*c0 + ig*cg;
            hy0 = og * tanhf_(c0);
            if (t == TSTEPS - 1) {
                int k = jbase + ej;
                out[OFF_HN + eb*512 + k] = hy0;
                out[OFF_CN + eb*512 + k] = c0;
                out[OFF_IG + eb*512 + k] = ig;
                out[OFF_FG + eb*512 + k] = fg;
                out[OFF_OG + eb*512 + k] = og;
            }
        }
        {
            int ej2 = ej + 8;
            float v0 = part[0][eb][ 0 + ej2] + part[1][eb][ 0 + ej2] + bias_lds[0][ej2];
            float v1 = part[0][eb][16 + ej2] + part[1][eb][16 + ej2] + bias_lds[1][ej2];
            float v2 = part[0][eb][32 + ej2] + part[1][eb][32 + ej2] + bias_lds[2][ej2];
            float v3 = part[0][eb][48 + ej2] + part[1][eb][48 + ej2] + bias_lds[3][ej2];
            float ig = sigf(v0), fg = sigf(v1), cg = tanhf_(v2), og = sigf(v3);
            c1 = fg*c1 + ig*cg;
            hy1 = og * tanhf_(c1);
            if (t == TSTEPS - 1) {
                int k = jbase + ej2;
                out[OFF_HN + eb*512 + k] = hy1;
                out[OFF_CN + eb*512 + k] = c1;
                out[OFF_IG + eb*512 + k] = ig;
                out[OFF_FG + eb*512 + k] = fg;
                out[OFF_OG + eb*512 + k] = og;
            }
        }

        // main output: out[h][t*32 + b]  (coalesced over eb)
        out[(size_t)(jbase + ej)     * 65536 + t*32 + eb] = hy0;
        out[(size_t)(jbase + ej + 8) * 65536 + t*32 + eb] = hy1;

        // h -> fragment-major global (block writes its own kf = bk slab)
        {
            int k  = jbase + ej;                  // k8 = 2*bk, kf = bk, lanehalf 0
            hnxt[bk*512 + eb*8 + ej]        = (_Float16)hy0;
            hnxt[bk*512 + (32 + eb)*8 + ej] = (_Float16)hy1;   // k+8: lanehalf 1
            (void)k;
        }

        // ---- device-scope step barrier ----
        __syncthreads();
        if (tid == 0) {
            __threadfence();   // release: push h writes to coherence point (L3)
            __hip_atomic_fetch_add(CNT, 1u, __ATOMIC_RELAXED, __HIP_MEMORY_SCOPE_AGENT);
            const unsigned tgt = (unsigned)NBLK * (unsigned)(t + 1);
            while (__hip_atomic_load(CNT, __ATOMIC_RELAXED, __HIP_MEMORY_SCOPE_AGENT) < tgt) {
                __builtin_amdgcn_s_sleep(1);
            }
            __threadfence();   // acquire: invalidate stale L1/L2 before next h reads
        }
        __syncthreads();
    }
}

// ---------------------------------------------------------------------------
extern "C" void kernel_launch(void* const* d_in, const int* in_sizes, int n_in,
                              void* d_out, int out_size, void* d_ws, size_t ws_size,
                              hipStream_t stream)
{
    const float* x  = (const float*)d_in[0];
    const float* hx = (const float*)d_in[1];
    const float* cx = (const float*)d_in[2];

    Ptrs P;
    for (int i = 0; i < 16; ++i) P.p[i] = (const float*)d_in[3 + i];

    char* ws = (char*)d_ws;
    _Float16* WH16 = (_Float16*)(ws + WS_WH);
    _Float16* WX16 = (_Float16*)(ws + WS_WX);
    _Float16* XG   = (_Float16*)(ws + WS_XG);
    _Float16* HG   = (_Float16*)(ws + WS_HG);
    float*    BIAS = (float*)   (ws + WS_BIAS);
    unsigned* CNT  = (unsigned*)(ws + WS_CNT);

    float* out = (float*)d_out;

    setup_kernel<<<6161, 256, 0, stream>>>(P, hx, WH16, WX16, BIAS, HG, CNT);
    xconv_kernel<<<8192, 256, 0, stream>>>(x, XG);
    lstm_rec<<<NBLK, 256, 0, stream>>>(cx, out, WH16, WX16, XG, HG, BIAS, CNT);
}

// Round 5
// 12127.406 us; speedup vs baseline: 1.0692x; 1.0692x over previous
//
#include <hip/hip_runtime.h>
#include <hip/hip_bf16.h>

// ---------------------------------------------------------------------------
// LSTM (B=32, T=2048, I=256, H=512), batch_first, fp32 in/out.
// Persistent cooperative kernel, weights register-resident as MFMA B-frags
// (fp16). Round 2 design (3rd resubmit after infra timeouts): h exchange via
// AGENT-scope relaxed atomics (sc1, bypasses L2 -> no threadfence L2 wbinv),
// per-block ready flags polled lane-parallel, x-part MFMAs hoisted before the
// h-wait. XG/weights stay L2-cached.
// ---------------------------------------------------------------------------

typedef _Float16 f16x8 __attribute__((ext_vector_type(8)));
typedef float    f32x16 __attribute__((ext_vector_type(16)));

#define NBLK   32
#define TSTEPS 2048

// ws layout (bytes)
#define WS_WH    0            // 4*512*512*2   = 2,097,152
#define WS_WX    2097152      // 4*512*256*2   = 1,048,576
#define WS_XG    3145728      // 2048*16*64*8*2= 33,554,432
#define WS_HG    36700160     // 2*32*64*8*2   = 65,536
#define WS_BIAS  36765696     // 4*512*4       = 8,192
#define WS_FLG   36773888     // 32*4          = 128

#define OUT_MAIN 33554432     // 512*65536
#define OFF_HN   (OUT_MAIN)
#define OFF_CN   (OUT_MAIN + 16384)
#define OFF_IG   (OUT_MAIN + 32768)
#define OFF_FG   (OUT_MAIN + 49152)
#define OFF_OG   (OUT_MAIN + 65536)

struct Ptrs { const float* p[16]; };   // p[0..7]=Wii,bii,..Wio,bio  p[8..15]=Whi,bhi,..Who,bho

__device__ __forceinline__ float sigf(float v) {
    return 1.0f / (1.0f + __expf(-v));
}
__device__ __forceinline__ float tanhf_(float v) {
    float a = fabsf(v);
    float e = __expf(-2.0f * a);
    float r = (1.0f - e) / (1.0f + e);
    return v < 0.0f ? -r : r;
}

// ---------------------------------------------------------------------------
// Setup: convert weights to fp16, combine biases, init h fragment buffer, flags
// ---------------------------------------------------------------------------
__global__ void setup_kernel(Ptrs P, const float* __restrict__ hx,
                             _Float16* __restrict__ WH16, _Float16* __restrict__ WX16,
                             float* __restrict__ BIAS, _Float16* __restrict__ HG,
                             unsigned* __restrict__ FLAGS)
{
    int idx = blockIdx.x * 256 + threadIdx.x;
    if (idx < 1048576) {                       // WH16[g][j][k] <- Whg (row-major copy)
        int g = idx >> 18; int r = idx & 262143;
        WH16[idx] = (_Float16)P.p[8 + 2*g][r];
    } else if (idx < 1572864) {                // WX16[g][j][i]
        int j = idx - 1048576; int g = j >> 17; int r = j & 131071;
        WX16[j] = (_Float16)P.p[2*g][r];
    } else if (idx < 1574912) {                // combined bias
        int j = idx - 1572864; int g = j >> 9; int c = j & 511;
        BIAS[j] = P.p[2*g + 1][c] + P.p[8 + 2*g + 1][c];
    } else if (idx < 1576960) {                // h0 fragment-major chunks
        int ch = idx - 1574912;                // 0..2047 : [kf 0..31][lane 0..63]
        int kf = ch >> 6; int lane = ch & 63;
        int b = lane & 31; int k0 = (kf*2 + (lane >> 5)) * 8;
        f16x8 o;
        #pragma unroll
        for (int e = 0; e < 8; ++e) o[e] = (_Float16)hx[b*512 + k0 + e];
        *(f16x8*)(HG + (size_t)ch * 8) = o;
    } else if (idx < 1576992) {                // step-ready flags
        FLAGS[idx - 1576960] = 0u;
    }
}

// ---------------------------------------------------------------------------
// x -> fp16 fragment-major per step: XG[t][kf 0..15][lane 0..63][8]
// ---------------------------------------------------------------------------
__global__ void xconv_kernel(const float* __restrict__ x, _Float16* __restrict__ XG)
{
    int ch = blockIdx.x * 256 + threadIdx.x;   // 0 .. 2,097,151
    int t = ch >> 10; int rest = ch & 1023;
    int kf = rest >> 6; int lane = rest & 63;
    int b = lane & 31; int i0 = (kf*2 + (lane >> 5)) * 8;
    const float* src = x + ((size_t)b * 2048 + t) * 256 + i0;
    float4 u = *(const float4*)src;
    float4 v = *(const float4*)(src + 4);
    f16x8 o;
    o[0]=(_Float16)u.x; o[1]=(_Float16)u.y; o[2]=(_Float16)u.z; o[3]=(_Float16)u.w;
    o[4]=(_Float16)v.x; o[5]=(_Float16)v.y; o[6]=(_Float16)v.z; o[7]=(_Float16)v.w;
    *(f16x8*)(XG + (size_t)ch * 8) = o;
}

// ---------------------------------------------------------------------------
// Persistent recurrent kernel: 32 blocks x 256 threads
// block bk owns h-cols [bk*16, bk*16+16) for all 4 gates (64 gate-cols)
// wave w: kh = w&1 (K-half of 768=512h+256x), cs = w>>1 (colset of 32)
// ---------------------------------------------------------------------------
__global__ __launch_bounds__(256, 1) void lstm_rec(
    const float* __restrict__ cx, float* __restrict__ out,
    const _Float16* __restrict__ WH16, const _Float16* __restrict__ WX16,
    const _Float16* __restrict__ XG, _Float16* __restrict__ HG,
    const float* __restrict__ BIAS, unsigned* __restrict__ FLAGS)
{
    __shared__ float part[2][32][66];
    __shared__ float bias_lds[4][16];

    const int tid = threadIdx.x;
    const int bk  = blockIdx.x;
    const int jbase = bk * 16;
    const int w  = tid >> 6;
    const int l  = tid & 63;
    const int kh = w & 1;
    const int cs = w >> 1;
    const int n  = l & 31;
    const int kg = l >> 5;

    if (tid < 64) bias_lds[tid >> 4][tid & 15] = BIAS[(tid >> 4)*512 + jbase + (tid & 15)];

    // ---- register-resident weights: 24 B-fragments per wave ----
    const int c_loc = cs*32 + n;          // local gate-col 0..63
    const int g  = c_loc >> 4;            // gate 0..3
    const int jr = jbase + (c_loc & 15);  // weight row (output col j)

    f16x8 bf[24];
    #pragma unroll
    for (int m = 0; m < 16; ++m) {        // h part: k = (kh*16+m)*16 + kg*8
        int k = (kh*16 + m)*16 + kg*8;
        bf[m] = *(const f16x8*)(WH16 + ((size_t)g*512 + jr)*512 + k);
    }
    #pragma unroll
    for (int m = 0; m < 8; ++m) {         // x part
        int i = (kh*8 + m)*16 + kg*8;
        bf[16 + m] = *(const f16x8*)(WX16 + ((size_t)g*512 + jr)*256 + i);
    }

    // ---- elementwise ownership: (b=eb, j=jbase+2*ep and jbase+2*ep+1) ----
    const int eb = tid & 31;
    const int ep = tid >> 5;              // 0..7
    float c0 = cx[eb*512 + jbase + 2*ep];
    float c1 = cx[eb*512 + jbase + 2*ep + 1];
    // packed-dword index into h fragment buffer for (hy0,hy1)
    const int hdw = bk*256 + (ep < 4 ? (eb*4 + ep) : ((32 + eb)*4 + (ep - 4)));

    __syncthreads();

    for (int t = 0; t < TSTEPS; ++t) {
        // ---- x-part first: plain loads (L2-warm) + MFMA, independent of h ----
        f16x8 ax[8];
        #pragma unroll
        for (int m = 0; m < 8; ++m)
            ax[m] = *(const f16x8*)(XG + (size_t)t*8192 + (size_t)(kh*8 + m)*512 + l*8);

        f32x16 accA, accB;
        #pragma unroll
        for (int i = 0; i < 16; ++i) { accA[i] = 0.0f; accB[i] = 0.0f; }

        #pragma unroll
        for (int m = 0; m < 8; m += 2) {
            accA = __builtin_amdgcn_mfma_f32_32x32x16_f16(ax[m],   bf[16+m],   accA, 0, 0, 0);
            accB = __builtin_amdgcn_mfma_f32_32x32x16_f16(ax[m+1], bf[16+m+1], accB, 0, 0, 0);
        }

        // ---- wait until all blocks have published h_t (flags >= t) ----
        if (w == 0) {
            for (;;) {
                unsigned v = __hip_atomic_load(FLAGS + (l & 31), __ATOMIC_RELAXED,
                                               __HIP_MEMORY_SCOPE_AGENT);
                if (__all((int)(v >= (unsigned)t))) break;
                __builtin_amdgcn_s_sleep(1);
            }
        }
        __syncthreads();

        // ---- h-part: coherent (L2-bypassing) fragment loads + MFMA ----
        const unsigned long long* hcur64 =
            (const unsigned long long*)HG + (size_t)(t & 1) * 4096;
        f16x8 ah[16];
        #pragma unroll
        for (int m = 0; m < 16; ++m) {
            int bofs = ((kh*16 + m)*64 + l) * 2;     // u64 units
            union { f16x8 v; unsigned long long u[2]; } tq;
            tq.u[0] = __hip_atomic_load(hcur64 + bofs,     __ATOMIC_RELAXED, __HIP_MEMORY_SCOPE_AGENT);
            tq.u[1] = __hip_atomic_load(hcur64 + bofs + 1, __ATOMIC_RELAXED, __HIP_MEMORY_SCOPE_AGENT);
            ah[m] = tq.v;
        }
        #pragma unroll
        for (int m = 0; m < 16; m += 2) {
            accA = __builtin_amdgcn_mfma_f32_32x32x16_f16(ah[m],   bf[m],   accA, 0, 0, 0);
            accB = __builtin_amdgcn_mfma_f32_32x32x16_f16(ah[m+1], bf[m+1], accB, 0, 0, 0);
        }

        // partial gate pre-activations -> LDS (D layout: col=l&31, row=(r&3)+8*(r>>2)+4*kg)
        #pragma unroll
        for (int r = 0; r < 16; ++r) {
            int b = (r & 3) + 8*(r >> 2) + 4*kg;
            part[kh][b][c_loc] = accA[r] + accB[r];
        }
        __syncthreads();

        // ---- elementwise: reduce K-halves, activations, state update ----
        const int ca = 2*ep, cb = 2*ep + 1;
        float hy0, hy1, ig0, fg0, og0, ig1, fg1, og1;
        {
            float v0 = part[0][eb][ 0 + ca] + part[1][eb][ 0 + ca] + bias_lds[0][ca];
            float v1 = part[0][eb][16 + ca] + part[1][eb][16 + ca] + bias_lds[1][ca];
            float v2 = part[0][eb][32 + ca] + part[1][eb][32 + ca] + bias_lds[2][ca];
            float v3 = part[0][eb][48 + ca] + part[1][eb][48 + ca] + bias_lds[3][ca];
            ig0 = sigf(v0); fg0 = sigf(v1); float cg = tanhf_(v2); og0 = sigf(v3);
            c0 = fg0*c0 + ig0*cg;
            hy0 = og0 * tanhf_(c0);
        }
        {
            float v0 = part[0][eb][ 0 + cb] + part[1][eb][ 0 + cb] + bias_lds[0][cb];
            float v1 = part[0][eb][16 + cb] + part[1][eb][16 + cb] + bias_lds[1][cb];
            float v2 = part[0][eb][32 + cb] + part[1][eb][32 + cb] + bias_lds[2][cb];
            float v3 = part[0][eb][48 + cb] + part[1][eb][48 + cb] + bias_lds[3][cb];
            ig1 = sigf(v0); fg1 = sigf(v1); float cg = tanhf_(v2); og1 = sigf(v3);
            c1 = fg1*c1 + ig1*cg;
            hy1 = og1 * tanhf_(c1);
        }

        // ---- publish h_{t+1}: one packed coherent dword per thread ----
        {
            union { unsigned u; _Float16 h[2]; } pk;
            pk.h[0] = (_Float16)hy0; pk.h[1] = (_Float16)hy1;
            unsigned* hnxt32 = (unsigned*)HG + (size_t)((t + 1) & 1) * 8192;
            __hip_atomic_store(hnxt32 + hdw, pk.u, __ATOMIC_RELAXED,
                               __HIP_MEMORY_SCOPE_AGENT);
        }
        asm volatile("s_waitcnt vmcnt(0)" ::: "memory");  // drain this wave's sc1 stores
        __syncthreads();                                   // all waves drained
        if (tid == 0)
            __hip_atomic_store(FLAGS + bk, (unsigned)(t + 1), __ATOMIC_RELAXED,
                               __HIP_MEMORY_SCOPE_AGENT);

        // ---- outputs (plain stores, off the critical path, after flag) ----
        out[(size_t)(jbase + ca) * 65536 + t*32 + eb] = hy0;
        out[(size_t)(jbase + cb) * 65536 + t*32 + eb] = hy1;
        if (t == TSTEPS - 1) {
            int k0 = jbase + ca, k1 = jbase + cb;
            out[OFF_HN + eb*512 + k0] = hy0;  out[OFF_HN + eb*512 + k1] = hy1;
            out[OFF_CN + eb*512 + k0] = c0;   out[OFF_CN + eb*512 + k1] = c1;
            out[OFF_IG + eb*512 + k0] = ig0;  out[OFF_IG + eb*512 + k1] = ig1;
            out[OFF_FG + eb*512 + k0] = fg0;  out[OFF_FG + eb*512 + k1] = fg1;
            out[OFF_OG + eb*512 + k0] = og0;  out[OFF_OG + eb*512 + k1] = og1;
        }
    }
}

// ---------------------------------------------------------------------------
extern "C" void kernel_launch(void* const* d_in, const int* in_sizes, int n_in,
                              void* d_out, int out_size, void* d_ws, size_t ws_size,
                              hipStream_t stream)
{
    const float* x  = (const float*)d_in[0];
    const float* hx = (const float*)d_in[1];
    const float* cx = (const float*)d_in[2];

    Ptrs P;
    for (int i = 0; i < 16; ++i) P.p[i] = (const float*)d_in[3 + i];

    char* ws = (char*)d_ws;
    _Float16* WH16 = (_Float16*)(ws + WS_WH);
    _Float16* WX16 = (_Float16*)(ws + WS_WX);
    _Float16* XG   = (_Float16*)(ws + WS_XG);
    _Float16* HG   = (_Float16*)(ws + WS_HG);
    float*    BIAS = (float*)   (ws + WS_BIAS);
    unsigned* FLAGS= (unsigned*)(ws + WS_FLG);

    float* out = (float*)d_out;

    setup_kernel<<<6161, 256, 0, stream>>>(P, hx, WH16, WX16, BIAS, HG, FLAGS);
    xconv_kernel<<<8192, 256, 0, stream>>>(x, XG);
    lstm_rec<<<NBLK, 256, 0, stream>>>(cx, out, WH16, WX16, XG, HG, BIAS, FLAGS);
}